// Round 4
// baseline (325.336 us; speedup 1.0000x reference)
//
#include <hip/hip_runtime.h>

// Problem: B=2048, H=4, D=4096, M=8, dm=512.
// s_flat[r,j] = sum_h x[b,h,m*512+c]*lW[m,h] + lb[m],
//   m=r>>8, b=(r&255)*8+(j>>9), c=j&511.
// out[r,n] = sigmoid(sum_j s_flat[r,j]*pW[n,j] + pb[n]),  out fp32 [2048][4096].

#define MD 2048
#define ND 4096
#define KD 4096

typedef __attribute__((ext_vector_type(8))) __bf16 bf16x8;
typedef __attribute__((ext_vector_type(4))) float f32x4;
typedef __attribute__((ext_vector_type(4))) float nf4;   // native vec for nt builtins

static __device__ __forceinline__ unsigned short f2bf(float f) {
  union { float f; unsigned int u; } v; v.f = f;
  unsigned int u = v.u;
  u += 0x7FFFu + ((u >> 16) & 1u);   // RNE
  return (unsigned short)(u >> 16);
}

static __device__ __forceinline__ nf4 ntload4(const float* p) {
  return __builtin_nontemporal_load((const nf4*)p);
}

// Grid-stride prep, 2048 blocks x 256 threads, 4 iters/thread.
// blocks [0,1024): s_flat (bf16), 8 j's per thread-iter (16B store).
// blocks [1024,2048): proj_W fp32 -> bf16, 16 floats per thread-iter.
// R2 post-mortem: one-shot threads with 4 loads in flight ran at 1.8 TB/s;
// grid-stride + 8 loads in flight + 16B stores targets the ~6 TB/s floor.
__global__ __launch_bounds__(256) void prep_kernel(
    const float* __restrict__ x, const float* __restrict__ lW,
    const float* __restrict__ lb, const float* __restrict__ pW,
    unsigned short* __restrict__ sB, unsigned short* __restrict__ wB) {
  int bid = blockIdx.x;
  int tid = threadIdx.x;
  if (bid < 1024) {
    int g = bid * 256 + tid;                  // stride 2^18, N1 = 2^20
    for (int idx = g; idx < (1 << 20); idx += (1 << 18)) {
      int j8 = idx << 3;                      // flat index r*4096 + j, j8 % 8 == 0
      int r = j8 >> 12;
      int j = j8 & 4095;
      int m = r >> 8;
      int b = ((r & 255) << 3) + (j >> 9);
      int c = j & 511;                        // 8 consecutive j stay in one 512-group
      const float* xp = x + ((long)b << 14) + m * 512 + c;
      float w0 = lW[m * 4 + 0], w1 = lW[m * 4 + 1], w2 = lW[m * 4 + 2], w3 = lW[m * 4 + 3];
      float bb = lb[m];
      nf4 xa0 = ntload4(xp);
      nf4 xb0 = ntload4(xp + 4);
      nf4 xa1 = ntload4(xp + 4096);
      nf4 xb1 = ntload4(xp + 4100);
      nf4 xa2 = ntload4(xp + 8192);
      nf4 xb2 = ntload4(xp + 8196);
      nf4 xa3 = ntload4(xp + 12288);
      nf4 xb3 = ntload4(xp + 12292);
      float v0 = bb + xa0.x * w0 + xa1.x * w1 + xa2.x * w2 + xa3.x * w3;
      float v1 = bb + xa0.y * w0 + xa1.y * w1 + xa2.y * w2 + xa3.y * w3;
      float v2 = bb + xa0.z * w0 + xa1.z * w1 + xa2.z * w2 + xa3.z * w3;
      float v3 = bb + xa0.w * w0 + xa1.w * w1 + xa2.w * w2 + xa3.w * w3;
      float v4 = bb + xb0.x * w0 + xb1.x * w1 + xb2.x * w2 + xb3.x * w3;
      float v5 = bb + xb0.y * w0 + xb1.y * w1 + xb2.y * w2 + xb3.y * w3;
      float v6 = bb + xb0.z * w0 + xb1.z * w1 + xb2.z * w2 + xb3.z * w3;
      float v7 = bb + xb0.w * w0 + xb1.w * w1 + xb2.w * w2 + xb3.w * w3;
      uint4 pk;
      pk.x = (unsigned)f2bf(v0) | ((unsigned)f2bf(v1) << 16);
      pk.y = (unsigned)f2bf(v2) | ((unsigned)f2bf(v3) << 16);
      pk.z = (unsigned)f2bf(v4) | ((unsigned)f2bf(v5) << 16);
      pk.w = (unsigned)f2bf(v6) | ((unsigned)f2bf(v7) << 16);
      *(uint4*)(sB + j8) = pk;                // 16B store
    }
  } else {
    int g = (bid - 1024) * 256 + tid;         // stride 2^18, N2 = 2^20 (x16 floats)
    for (int idx = g; idx < (1 << 20); idx += (1 << 18)) {
      long off = (long)idx << 4;              // 16 floats per iter
      nf4 a = ntload4(pW + off);
      nf4 b4 = ntload4(pW + off + 4);
      nf4 c4 = ntload4(pW + off + 8);
      nf4 d4 = ntload4(pW + off + 12);
      uint4 p0, p1;
      p0.x = (unsigned)f2bf(a.x) | ((unsigned)f2bf(a.y) << 16);
      p0.y = (unsigned)f2bf(a.z) | ((unsigned)f2bf(a.w) << 16);
      p0.z = (unsigned)f2bf(b4.x) | ((unsigned)f2bf(b4.y) << 16);
      p0.w = (unsigned)f2bf(b4.z) | ((unsigned)f2bf(b4.w) << 16);
      p1.x = (unsigned)f2bf(c4.x) | ((unsigned)f2bf(c4.y) << 16);
      p1.y = (unsigned)f2bf(c4.z) | ((unsigned)f2bf(c4.w) << 16);
      p1.z = (unsigned)f2bf(d4.x) | ((unsigned)f2bf(d4.y) << 16);
      p1.w = (unsigned)f2bf(d4.z) | ((unsigned)f2bf(d4.w) << 16);
      *(uint4*)(wB + off) = p0;
      *(uint4*)(wB + off + 8) = p1;
    }
  }
}

// m97-recipe GEMM: C[2048][4096] = S[2048][4096] * W[4096][4096]^T (both bf16,
// K contiguous), epilogue sigmoid(acc + pb[n]) -> fp32.
// 128x128 block tile, BK=64, 4 waves in 2x2, each wave 4x4 of 16x16x32 MFMA.
//
// LDS layout: [row][64] ushorts (128 B = exactly 32 banks per row) with XOR
// chunk swizzle: LDS slot (row, cc) holds global 16B-chunk (row, cc ^ (row&7)).
// Without the swizzle, fragment reads are 16-way bank-conflicted (R1: 2.5e7
// SQ_LDS_BANK_CONFLICT -> R2 fix: gemm 104 -> 81.5 us).
#define BM 128
#define BN 128
#define BK 64

__global__ __launch_bounds__(256) void gemm_kernel(
    const unsigned short* __restrict__ S, const unsigned short* __restrict__ W,
    const float* __restrict__ pb, float* __restrict__ out) {
  __shared__ unsigned short As[BM * BK];   // unpadded (global_load_lds)
  __shared__ unsigned short Bs[BN * BK];
  int tid = threadIdx.x;
  int lane = tid & 63;
  int wave = tid >> 6;
  int n0 = blockIdx.x * BN;   // 32 n-tiles
  int r0 = blockIdx.y * BM;   // 16 m-tiles
  int wr = wave >> 1, wc = wave & 1;

  int srow = (wave << 5) + (lane >> 3);            // + i*8 per issue
  int scol = (((lane & 7) ^ (lane >> 3)) << 3);    // swizzled k-element offset
  const unsigned short* gA = S + (long)(r0 + srow) * KD + scol;
  const unsigned short* gB = W + (long)(n0 + srow) * KD + scol;
  unsigned short* lA = &As[(wave << 5) * BK];  // wave-uniform base; HW adds lane*16B
  unsigned short* lB = &Bs[(wave << 5) * BK];

  f32x4 acc[4][4] = {};

  for (int kt = 0; kt < KD; kt += BK) {
    __syncthreads();
#pragma unroll
    for (int i = 0; i < 4; ++i) {
      __builtin_amdgcn_global_load_lds(
          (const __attribute__((address_space(1))) unsigned int*)(gA + (long)i * 8 * KD + kt),
          (__attribute__((address_space(3))) unsigned int*)(lA + i * 8 * BK), 16, 0, 0);
      __builtin_amdgcn_global_load_lds(
          (const __attribute__((address_space(1))) unsigned int*)(gB + (long)i * 8 * KD + kt),
          (__attribute__((address_space(3))) unsigned int*)(lB + i * 8 * BK), 16, 0, 0);
    }
    __syncthreads();
#pragma unroll
    for (int ks = 0; ks < 2; ++ks) {
      // fragment chunk kc_lin = ks*4 + (lane>>4); physical chunk =
      // kc_lin ^ (row & 7); row&7 == lane&7 for all t (t*16 is 0 mod 8).
      int swz = (((ks << 2) + (lane >> 4)) ^ (lane & 7)) << 3;
      bf16x8 af[4], bfr[4];
#pragma unroll
      for (int t = 0; t < 4; ++t) {
        af[t]  = *(const bf16x8*)&As[((wr << 6) + t * 16 + (lane & 15)) * BK + swz];
        bfr[t] = *(const bf16x8*)&Bs[((wc << 6) + t * 16 + (lane & 15)) * BK + swz];
      }
#pragma unroll
      for (int mt = 0; mt < 4; ++mt)
#pragma unroll
        for (int nt = 0; nt < 4; ++nt)
          acc[mt][nt] = __builtin_amdgcn_mfma_f32_16x16x32_bf16(af[mt], bfr[nt], acc[mt][nt], 0, 0, 0);
    }
  }

  // epilogue: C/D layout col=lane&15, row=(lane>>4)*4+i  [m89/m91]
#pragma unroll
  for (int nt = 0; nt < 4; ++nt) {
    int col = n0 + (wc << 6) + nt * 16 + (lane & 15);
    float pbv = pb[col];
#pragma unroll
    for (int mt = 0; mt < 4; ++mt) {
      int row = r0 + (wr << 6) + mt * 16 + ((lane >> 4) << 2);
#pragma unroll
      for (int i = 0; i < 4; ++i) {
        float v = acc[mt][nt][i] + pbv;
        out[(long)(row + i) * ND + col] = 1.0f / (1.0f + __expf(-v));
      }
    }
  }
}

extern "C" void kernel_launch(void* const* d_in, const int* in_sizes, int n_in,
                              void* d_out, int out_size, void* d_ws, size_t ws_size,
                              hipStream_t stream) {
  const float* x  = (const float*)d_in[0];   // (2048, 4, 4096)
  const float* lW = (const float*)d_in[1];   // (8, 4)
  const float* lb = (const float*)d_in[2];   // (8,)
  const float* pW = (const float*)d_in[3];   // (4096, 4096)
  const float* pb = (const float*)d_in[4];   // (4096,)
  float* out = (float*)d_out;                // (2048, 4096) fp32

  unsigned short* sB = (unsigned short*)d_ws;          // 2048*4096 bf16 = 16 MiB
  unsigned short* wB = sB + (long)MD * KD;             // 4096*4096 bf16 = 32 MiB

  prep_kernel<<<2048, 256, 0, stream>>>(x, lW, lb, pW, sB, wB);
  gemm_kernel<<<dim3(32, 16), 256, 0, stream>>>(sB, wB, pb, out);
}

// Round 5
// 316.104 us; speedup vs baseline: 1.0292x; 1.0292x over previous
//
#include <hip/hip_runtime.h>

// Problem: B=2048, H=4, D=4096, M=8, dm=512.
// s_flat[r,j] = sum_h x[b,h,m*512+c]*lW[m,h] + lb[m],
//   m=r>>8, b=(r&255)*8+(j>>9), c=j&511.
// out[r,n] = sigmoid(sum_j s_flat[r,j]*pW[n,j] + pb[n]),  out fp32 [2048][4096].

#define MD 2048
#define ND 4096
#define KD 4096

typedef __attribute__((ext_vector_type(8))) __bf16 bf16x8;
typedef __attribute__((ext_vector_type(4))) float f32x4;

static __device__ __forceinline__ unsigned short f2bf(float f) {
  union { float f; unsigned int u; } v; v.f = f;
  unsigned int u = v.u;
  u += 0x7FFFu + ((u >> 16) & 1u);   // RNE
  return (unsigned short)(u >> 16);
}

// Prep v3 (R4 post-mortem: grid-stride+nt regressed prep 83.5->~91; nt loses
// L3 hits on restore-resident x/pW). One-shot threads, 8x16B loads in flight,
// plain cacheable loads, 16B stores.
// blocks [0,4096): s_flat (bf16), 8 j's per thread.
// blocks [4096,8192): proj_W fp32 -> bf16, 16 floats per thread.
__global__ __launch_bounds__(256) void prep_kernel(
    const float* __restrict__ x, const float* __restrict__ lW,
    const float* __restrict__ lb, const float* __restrict__ pW,
    unsigned short* __restrict__ sB, unsigned short* __restrict__ wB) {
  int bid = blockIdx.x;
  int tid = threadIdx.x;
  if (bid < 4096) {
    int g = bid * 256 + tid;                  // 0 .. 2^20
    int j8 = g << 3;                          // flat index r*4096 + j, j8 % 8 == 0
    int r = j8 >> 12;
    int j = j8 & 4095;
    int m = r >> 8;
    int b = ((r & 255) << 3) + (j >> 9);
    int c = j & 511;                          // 8 consecutive j stay in one 512-group
    const float* xp = x + ((long)b << 14) + m * 512 + c;
    float w0 = lW[m * 4 + 0], w1 = lW[m * 4 + 1], w2 = lW[m * 4 + 2], w3 = lW[m * 4 + 3];
    float bb = lb[m];
    float4 xa0 = *(const float4*)(xp);
    float4 xb0 = *(const float4*)(xp + 4);
    float4 xa1 = *(const float4*)(xp + 4096);
    float4 xb1 = *(const float4*)(xp + 4100);
    float4 xa2 = *(const float4*)(xp + 8192);
    float4 xb2 = *(const float4*)(xp + 8196);
    float4 xa3 = *(const float4*)(xp + 12288);
    float4 xb3 = *(const float4*)(xp + 12292);
    float v0 = bb + xa0.x * w0 + xa1.x * w1 + xa2.x * w2 + xa3.x * w3;
    float v1 = bb + xa0.y * w0 + xa1.y * w1 + xa2.y * w2 + xa3.y * w3;
    float v2 = bb + xa0.z * w0 + xa1.z * w1 + xa2.z * w2 + xa3.z * w3;
    float v3 = bb + xa0.w * w0 + xa1.w * w1 + xa2.w * w2 + xa3.w * w3;
    float v4 = bb + xb0.x * w0 + xb1.x * w1 + xb2.x * w2 + xb3.x * w3;
    float v5 = bb + xb0.y * w0 + xb1.y * w1 + xb2.y * w2 + xb3.y * w3;
    float v6 = bb + xb0.z * w0 + xb1.z * w1 + xb2.z * w2 + xb3.z * w3;
    float v7 = bb + xb0.w * w0 + xb1.w * w1 + xb2.w * w2 + xb3.w * w3;
    uint4 pk;
    pk.x = (unsigned)f2bf(v0) | ((unsigned)f2bf(v1) << 16);
    pk.y = (unsigned)f2bf(v2) | ((unsigned)f2bf(v3) << 16);
    pk.z = (unsigned)f2bf(v4) | ((unsigned)f2bf(v5) << 16);
    pk.w = (unsigned)f2bf(v6) | ((unsigned)f2bf(v7) << 16);
    *(uint4*)(sB + j8) = pk;                  // 16B store
  } else {
    int g = (bid - 4096) * 256 + tid;         // 0 .. 2^20, x16 floats
    long off = (long)g << 4;
    float4 a = *(const float4*)(pW + off);
    float4 b4 = *(const float4*)(pW + off + 4);
    float4 c4 = *(const float4*)(pW + off + 8);
    float4 d4 = *(const float4*)(pW + off + 12);
    uint4 p0, p1;
    p0.x = (unsigned)f2bf(a.x) | ((unsigned)f2bf(a.y) << 16);
    p0.y = (unsigned)f2bf(a.z) | ((unsigned)f2bf(a.w) << 16);
    p0.z = (unsigned)f2bf(b4.x) | ((unsigned)f2bf(b4.y) << 16);
    p0.w = (unsigned)f2bf(b4.z) | ((unsigned)f2bf(b4.w) << 16);
    p1.x = (unsigned)f2bf(c4.x) | ((unsigned)f2bf(c4.y) << 16);
    p1.y = (unsigned)f2bf(c4.z) | ((unsigned)f2bf(c4.w) << 16);
    p1.z = (unsigned)f2bf(d4.x) | ((unsigned)f2bf(d4.y) << 16);
    p1.w = (unsigned)f2bf(d4.z) | ((unsigned)f2bf(d4.w) << 16);
    *(uint4*)(wB + off) = p0;
    *(uint4*)(wB + off + 8) = p1;
  }
}

// m97-recipe GEMM: C[2048][4096] = S[2048][4096] * W[4096][4096]^T (both bf16,
// K contiguous), epilogue sigmoid(acc + pb[n]) -> fp32.
// 128x128 block tile, BK=64, 4 waves in 2x2, each wave 4x4 of 16x16x32 MFMA.
//
// LDS layout: [row][64] ushorts (128 B = exactly 32 banks per row) with XOR
// chunk swizzle: LDS slot (row, cc) holds global 16B-chunk (row, cc ^ (row&7)).
// Without the swizzle, fragment reads are 16-way bank-conflicted (R1: 2.5e7
// SQ_LDS_BANK_CONFLICT -> R2 fix: gemm 104 -> 81.5 us, 843 TF).
#define BM 128
#define BN 128
#define BK 64

__global__ __launch_bounds__(256) void gemm_kernel(
    const unsigned short* __restrict__ S, const unsigned short* __restrict__ W,
    const float* __restrict__ pb, float* __restrict__ out) {
  __shared__ unsigned short As[BM * BK];   // unpadded (global_load_lds)
  __shared__ unsigned short Bs[BN * BK];
  int tid = threadIdx.x;
  int lane = tid & 63;
  int wave = tid >> 6;
  int n0 = blockIdx.x * BN;   // 32 n-tiles
  int r0 = blockIdx.y * BM;   // 16 m-tiles
  int wr = wave >> 1, wc = wave & 1;

  int srow = (wave << 5) + (lane >> 3);            // + i*8 per issue
  int scol = (((lane & 7) ^ (lane >> 3)) << 3);    // swizzled k-element offset
  const unsigned short* gA = S + (long)(r0 + srow) * KD + scol;
  const unsigned short* gB = W + (long)(n0 + srow) * KD + scol;
  unsigned short* lA = &As[(wave << 5) * BK];  // wave-uniform base; HW adds lane*16B
  unsigned short* lB = &Bs[(wave << 5) * BK];

  f32x4 acc[4][4] = {};

  for (int kt = 0; kt < KD; kt += BK) {
    __syncthreads();
#pragma unroll
    for (int i = 0; i < 4; ++i) {
      __builtin_amdgcn_global_load_lds(
          (const __attribute__((address_space(1))) unsigned int*)(gA + (long)i * 8 * KD + kt),
          (__attribute__((address_space(3))) unsigned int*)(lA + i * 8 * BK), 16, 0, 0);
      __builtin_amdgcn_global_load_lds(
          (const __attribute__((address_space(1))) unsigned int*)(gB + (long)i * 8 * KD + kt),
          (__attribute__((address_space(3))) unsigned int*)(lB + i * 8 * BK), 16, 0, 0);
    }
    __syncthreads();
#pragma unroll
    for (int ks = 0; ks < 2; ++ks) {
      // fragment chunk kc_lin = ks*4 + (lane>>4); physical chunk =
      // kc_lin ^ (row & 7); row&7 == lane&7 for all t (t*16 is 0 mod 8).
      int swz = (((ks << 2) + (lane >> 4)) ^ (lane & 7)) << 3;
      bf16x8 af[4], bfr[4];
#pragma unroll
      for (int t = 0; t < 4; ++t) {
        af[t]  = *(const bf16x8*)&As[((wr << 6) + t * 16 + (lane & 15)) * BK + swz];
        bfr[t] = *(const bf16x8*)&Bs[((wc << 6) + t * 16 + (lane & 15)) * BK + swz];
      }
#pragma unroll
      for (int mt = 0; mt < 4; ++mt)
#pragma unroll
        for (int nt = 0; nt < 4; ++nt)
          acc[mt][nt] = __builtin_amdgcn_mfma_f32_16x16x32_bf16(af[mt], bfr[nt], acc[mt][nt], 0, 0, 0);
    }
  }

  // epilogue: C/D layout col=lane&15, row=(lane>>4)*4+i  [m89/m91]
#pragma unroll
  for (int nt = 0; nt < 4; ++nt) {
    int col = n0 + (wc << 6) + nt * 16 + (lane & 15);
    float pbv = pb[col];
#pragma unroll
    for (int mt = 0; mt < 4; ++mt) {
      int row = r0 + (wr << 6) + mt * 16 + ((lane >> 4) << 2);
#pragma unroll
      for (int i = 0; i < 4; ++i) {
        float v = acc[mt][nt][i] + pbv;
        out[(long)(row + i) * ND + col] = 1.0f / (1.0f + __expf(-v));
      }
    }
  }
}

extern "C" void kernel_launch(void* const* d_in, const int* in_sizes, int n_in,
                              void* d_out, int out_size, void* d_ws, size_t ws_size,
                              hipStream_t stream) {
  const float* x  = (const float*)d_in[0];   // (2048, 4, 4096)
  const float* lW = (const float*)d_in[1];   // (8, 4)
  const float* lb = (const float*)d_in[2];   // (8,)
  const float* pW = (const float*)d_in[3];   // (4096, 4096)
  const float* pb = (const float*)d_in[4];   // (4096,)
  float* out = (float*)d_out;                // (2048, 4096) fp32

  unsigned short* sB = (unsigned short*)d_ws;          // 2048*4096 bf16 = 16 MiB
  unsigned short* wB = sB + (long)MD * KD;             // 4096*4096 bf16 = 32 MiB

  prep_kernel<<<8192, 256, 0, stream>>>(x, lW, lb, pW, sB, wB);
  gemm_kernel<<<dim3(32, 16), 256, 0, stream>>>(sB, wB, pb, out);
}